// Round 6
// baseline (927.918 us; speedup 1.0000x reference)
//
#include <hip/hip_runtime.h>
#include <math.h>

#define B_GROUPS 64
#define C_DIM 256
#define IN_DIM 512
#define EMB_DIM 512
#define NHEADS 8
#define HDIM 32

// ---------------- per-group starts via binary search ----------------
__global__ void starts_kernel(const int* __restrict__ bx, int nx,
                              const int* __restrict__ be, int ne,
                              int* __restrict__ sx, int* __restrict__ se) {
  int b = threadIdx.x;
  if (b > B_GROUPS) return;
  int lo = 0, hi = nx;
  while (lo < hi) { int mid = (lo + hi) >> 1; if (bx[mid] < b) lo = mid + 1; else hi = mid; }
  sx[b] = lo;
  lo = 0; hi = ne;
  while (lo < hi) { int mid = (lo + hi) >> 1; if (be[mid] < b) lo = mid + 1; else hi = mid; }
  se[b] = lo;
}

// ---------------- fp32 GEMM v3: 128x128 tile, 8x8/thread, double-buffered ----
// Two independent jobs per launch (block ranges split on blockIdx.x): fuses
// MLP1+qproj into one balanced launch and K|V into one A-pass.
// Schedule per k-step t (single barrier, T14 issue-early/write-late):
//   {issue global loads t+1} -> {compute buf[t&1]: 16kk x 64 FMA} ->
//   {vmcnt-wait + LDS-write buf^1} -> barrier.
// Bank audit: As/Ws compute reads broadcast or 2-way (free m136); As staging
// writes 2-way; Ws staging writes 8-way but only 2 instrs/step (off path).
// All register arrays fully unrolled, compile-time indexed (rule #20).
__global__ __launch_bounds__(256) void gemm_kernel(
    const float* __restrict__ A0, const float* __restrict__ W0,
    const float* __restrict__ bias0, float* __restrict__ C0,
    int M0, int K0, int N0, int act0,
    const float* __restrict__ A1, const float* __restrict__ W1p,
    const float* __restrict__ bias1, float* __restrict__ C1,
    int M1, int K1, int N1, int act1,
    int xsplit) {
  __shared__ float As[2][16][132];
  __shared__ float Ws[2][16][132];

  int bxi = blockIdx.x;
  const float *A, *W, *bias; float* C; int M, K, N, act;
  if (bxi < xsplit) { A = A0; W = W0; bias = bias0; C = C0; M = M0; K = K0; N = N0; act = act0; }
  else { bxi -= xsplit; A = A1; W = W1p; bias = bias1; C = C1; M = M1; K = K1; N = N1; act = act1; }
  int bm = blockIdx.y * 128;
  int bn = bxi * 128;
  if (bm >= M) return;

  int tid = threadIdx.x;
  int tx = tid & 15, ty = tid >> 4;
  int ar  = tid >> 1;            // 0..127  (A-tile row)
  int acb = (tid & 1) * 8;       // 0 or 8  (A-tile col block)
  int wr  = tid >> 4;            // 0..15   (W-tile row)
  int wcb = (tid & 15) * 8;      // 0..120  (W-tile col block)

  int gr = bm + ar;
  bool arow_ok = gr < M;
  const float* aplane = &A[(size_t)(arow_ok ? gr : 0) * K + acb];
  const float* wplane = &W[(size_t)wr * N + bn + wcb];

  float acc[2][2][4][4] = {};
  float4 sa0, sa1, sw0, sw1;   // staging registers

  // ---- prologue: stage k0 = 0 into buf 0
  {
    sa0 = make_float4(0.f, 0.f, 0.f, 0.f); sa1 = sa0;
    if (arow_ok) { sa0 = *(const float4*)aplane; sa1 = *(const float4*)(aplane + 4); }
    sw0 = *(const float4*)wplane; sw1 = *(const float4*)(wplane + 4);
    As[0][acb + 0][ar] = sa0.x; As[0][acb + 1][ar] = sa0.y;
    As[0][acb + 2][ar] = sa0.z; As[0][acb + 3][ar] = sa0.w;
    As[0][acb + 4][ar] = sa1.x; As[0][acb + 5][ar] = sa1.y;
    As[0][acb + 6][ar] = sa1.z; As[0][acb + 7][ar] = sa1.w;
    *(float4*)&Ws[0][wr][wcb]     = sw0;
    *(float4*)&Ws[0][wr][wcb + 4] = sw1;
  }
  __syncthreads();

  int nk = K >> 4;
  for (int t = 0; t < nk; ++t) {
    int cur = t & 1;
    bool more = (t + 1) < nk;
    if (more) {                      // issue next-tile global loads EARLY
      int k0 = (t + 1) << 4;
      sa0 = make_float4(0.f, 0.f, 0.f, 0.f); sa1 = sa0;
      if (arow_ok) { sa0 = *(const float4*)(aplane + k0); sa1 = *(const float4*)(aplane + k0 + 4); }
      const float* wp = wplane + (size_t)k0 * N;
      sw0 = *(const float4*)wp; sw1 = *(const float4*)(wp + 4);
    }
    // ---- compute current buffer (hides the global-load latency)
#pragma unroll
    for (int kk = 0; kk < 16; ++kk) {
      float a[2][4], w[2][4];
      *(float4*)a[0] = *(const float4*)&As[cur][kk][ty * 4];
      *(float4*)a[1] = *(const float4*)&As[cur][kk][64 + ty * 4];
      *(float4*)w[0] = *(const float4*)&Ws[cur][kk][tx * 4];
      *(float4*)w[1] = *(const float4*)&Ws[cur][kk][64 + tx * 4];
#pragma unroll
      for (int rh = 0; rh < 2; ++rh)
#pragma unroll
        for (int i = 0; i < 4; ++i) {
          float av = a[rh][i];
#pragma unroll
          for (int ch = 0; ch < 2; ++ch)
#pragma unroll
            for (int jj = 0; jj < 4; ++jj)
              acc[rh][ch][i][jj] += av * w[ch][jj];
        }
    }
    if (more) {                      // write next tile into the other buffer
      int nb = cur ^ 1;
      As[nb][acb + 0][ar] = sa0.x; As[nb][acb + 1][ar] = sa0.y;
      As[nb][acb + 2][ar] = sa0.z; As[nb][acb + 3][ar] = sa0.w;
      As[nb][acb + 4][ar] = sa1.x; As[nb][acb + 5][ar] = sa1.y;
      As[nb][acb + 6][ar] = sa1.z; As[nb][acb + 7][ar] = sa1.w;
      *(float4*)&Ws[nb][wr][wcb]     = sw0;
      *(float4*)&Ws[nb][wr][wcb + 4] = sw1;
    }
    __syncthreads();
  }

  // ---- epilogue
  float bias_lo[4], bias_hi[4];
  *(float4*)bias_lo = *(const float4*)&bias[bn + tx * 4];
  *(float4*)bias_hi = *(const float4*)&bias[bn + 64 + tx * 4];
#pragma unroll
  for (int rh = 0; rh < 2; ++rh)
#pragma unroll
    for (int i = 0; i < 4; ++i) {
      int orow = bm + rh * 64 + ty * 4 + i;
      if (orow >= M) continue;
#pragma unroll
      for (int ch = 0; ch < 2; ++ch) {
        float o[4];
#pragma unroll
        for (int jj = 0; jj < 4; ++jj) {
          float vv = acc[rh][ch][i][jj] + (ch ? bias_hi[jj] : bias_lo[jj]);
          if (act) vv = 0.5f * vv * (1.0f + erff(vv * 0.70710678118654752f));
          o[jj] = vv;
        }
        *(float4*)&C[(size_t)orow * N + bn + ch * 64 + tx * 4] = *(float4*)o;
      }
    }
}

// ---------------- LayerNorm over last dim (256), in-place ----------------
__global__ __launch_bounds__(256) void ln_kernel(float* __restrict__ h,
    const float* __restrict__ w, const float* __restrict__ b, int M) {
  int row = blockIdx.x * 4 + (threadIdx.x >> 6);
  int lane = threadIdx.x & 63;
  if (row >= M) return;
  float4 v = *(const float4*)&h[(size_t)row * C_DIM + lane * 4];
  float s  = v.x + v.y + v.z + v.w;
  float s2 = v.x * v.x + v.y * v.y + v.z * v.z + v.w * v.w;
#pragma unroll
  for (int off = 1; off < 64; off <<= 1) { s += __shfl_xor(s, off); s2 += __shfl_xor(s2, off); }
  float mu  = s  * (1.0f / 256.0f);
  float var = s2 * (1.0f / 256.0f) - mu * mu;
  float inv = rsqrtf(var + 1e-5f);
  float4 wv = *(const float4*)&w[lane * 4];
  float4 bv = *(const float4*)&b[lane * 4];
  float4 o;
  o.x = (v.x - mu) * inv * wv.x + bv.x;
  o.y = (v.y - mu) * inv * wv.y + bv.y;
  o.z = (v.z - mu) * inv * wv.z + bv.z;
  o.w = (v.w - mu) * inv * wv.w + bv.w;
  *(float4*)&h[(size_t)row * C_DIM + lane * 4] = o;
}

// ---------------- ragged masked flash attention (v5, unchanged) ----------------
// Measured R4/R5: VGPR 52, occ 35%, VALUBusy 65%, conflicts ~0, 311 us.
__global__ __launch_bounds__(256, 4) void attn_kernel(const float* __restrict__ q,
    const float* __restrict__ k, const float* __restrict__ v,
    const int* __restrict__ sx, const int* __restrict__ se,
    const int* __restrict__ emask, float* __restrict__ y) {
  int bid = blockIdx.x;
  int work = ((bid & 7) << 10) + (bid >> 3);   // same (b,hd) -> same XCD
  int qt = work & 15;
  int bh = work >> 4;
  int b  = bh & 63;
  int hd = bh >> 6;

  int xs = sx[b], lx = sx[b + 1] - xs;
  if (qt * 32 >= lx) return;
  int es = se[b], le = se[b + 1] - es;

  __shared__ float Ks[64][36];
  __shared__ float Vs[64][36];
  __shared__ float Ps[32][68];
  __shared__ float Bs[64];

  int tid = threadIdx.x;
  int j  = tid & 7;
  int qg = tid >> 3;   // 0..31

  int qr = qt * 32 + qg;
  bool qok = qr < lx;
  float qreg[32];
  {
    const float* qp = &q[(size_t)(xs + (qok ? qr : 0)) * C_DIM + hd * HDIM];
#pragma unroll
    for (int d4 = 0; d4 < 8; ++d4) {
      float4 t4 = *(const float4*)&qp[d4 * 4];
      qreg[d4 * 4 + 0] = t4.x; qreg[d4 * 4 + 1] = t4.y;
      qreg[d4 * 4 + 2] = t4.z; qreg[d4 * 4 + 3] = t4.w;
    }
  }

  float acc[4] = {};
  float mrun = -INFINITY, lrun = 0.f;
  const float scale = 0.17677669529663689f;  // 1/sqrt(32)

  for (int kc = 0; kc < le; kc += 64) {
    int nk = le - kc; if (nk > 64) nk = 64;
    {
      int r = tid >> 3, c = (tid & 7) * 4;
#pragma unroll
      for (int it = 0; it < 2; ++it) {
        int rr = r + it * 32;
        float4 kv = make_float4(0.f, 0.f, 0.f, 0.f);
        float4 vv = make_float4(0.f, 0.f, 0.f, 0.f);
        if (rr < nk) {
          size_t base = (size_t)(es + kc + rr) * C_DIM + hd * HDIM + c;
          kv = *(const float4*)&k[base];
          vv = *(const float4*)&v[base];
        }
        *(float4*)&Ks[rr][c] = kv;
        *(float4*)&Vs[rr][c] = vv;
      }
      if (tid < 64)
        Bs[tid] = (tid < nk && emask[es + kc + tid]) ? 0.f : -1e30f;
    }
    __syncthreads();

    float bs[8];
#pragma unroll
    for (int t = 0; t < 8; ++t) bs[t] = Bs[t * 8 + j];

    float p[8];
#pragma unroll
    for (int t = 0; t < 8; ++t) {
      const float* krow = &Ks[t * 8 + j][0];
      float s = 0.f;
#pragma unroll
      for (int d4 = 0; d4 < 8; ++d4) {
        float4 kv = *(const float4*)&krow[d4 * 4];
        s += qreg[d4 * 4 + 0] * kv.x + qreg[d4 * 4 + 1] * kv.y
           + qreg[d4 * 4 + 2] * kv.z + qreg[d4 * 4 + 3] * kv.w;
      }
      p[t] = s * scale + bs[t];
    }

    float mloc = p[0];
#pragma unroll
    for (int t = 1; t < 8; ++t) mloc = fmaxf(mloc, p[t]);
    mloc = fmaxf(mloc, __shfl_xor(mloc, 1));
    mloc = fmaxf(mloc, __shfl_xor(mloc, 2));
    mloc = fmaxf(mloc, __shfl_xor(mloc, 4));
    float mnew = fmaxf(mrun, mloc);
    float alpha = __expf(mrun - mnew);
    float lloc = 0.f;
#pragma unroll
    for (int t = 0; t < 8; ++t) {
      float pe = __expf(p[t] - mnew);
      Ps[qg][t * 8 + j] = pe;
      lloc += pe;
    }
    lloc += __shfl_xor(lloc, 1);
    lloc += __shfl_xor(lloc, 2);
    lloc += __shfl_xor(lloc, 4);
    lrun = lrun * alpha + lloc;
    mrun = mnew;
#pragma unroll
    for (int d = 0; d < 4; ++d) acc[d] *= alpha;

#pragma unroll
    for (int kk4 = 0; kk4 < 16; ++kk4) {
      float pa[4];
      *(float4*)pa = *(const float4*)&Ps[qg][kk4 * 4];
#pragma unroll
      for (int u = 0; u < 4; ++u) {
        float4 vv = *(const float4*)&Vs[kk4 * 4 + u][j * 4];
        acc[0] += pa[u] * vv.x; acc[1] += pa[u] * vv.y;
        acc[2] += pa[u] * vv.z; acc[3] += pa[u] * vv.w;
      }
    }
    __syncthreads();
  }

  if (qok) {
    float invl = (lrun > 0.f) ? 1.0f / lrun : 0.f;
    float4 o = make_float4(acc[0] * invl, acc[1] * invl,
                           acc[2] * invl, acc[3] * invl);
    *(float4*)&y[(size_t)(xs + qr) * C_DIM + hd * HDIM + j * 4] = o;
  }
}

// ---------------- launch ----------------
extern "C" void kernel_launch(void* const* d_in, const int* in_sizes, int n_in,
                              void* d_out, int out_size, void* d_ws, size_t ws_size,
                              hipStream_t stream) {
  const float* x    = (const float*)d_in[0];
  const int*   bx   = (const int*)d_in[1];
  const int*   be   = (const int*)d_in[2];
  const float* enc  = (const float*)d_in[3];
  const int*   msk  = (const int*)d_in[4];
  const float* Wq   = (const float*)d_in[5];
  const float* bq   = (const float*)d_in[6];
  const float* Wk   = (const float*)d_in[7];
  const float* bk   = (const float*)d_in[8];
  const float* Wv   = (const float*)d_in[9];
  const float* bv   = (const float*)d_in[10];
  const float* Wp   = (const float*)d_in[11];
  const float* bp   = (const float*)d_in[12];
  const float* W1   = (const float*)d_in[13];
  const float* b1   = (const float*)d_in[14];
  const float* W2   = (const float*)d_in[15];
  const float* b2   = (const float*)d_in[16];
  const float* lnw  = (const float*)d_in[17];
  const float* lnb  = (const float*)d_in[18];
  float* out = (float*)d_out;

  int Nx = in_sizes[0] / C_DIM;
  int Ne = in_sizes[3] / IN_DIM;
  int maxN = Nx > Ne ? Nx : Ne;

  char* ws = (char*)d_ws;
  int* sx = (int*)ws;          // 65 ints
  int* se = sx + 80;           // 65 ints
  float* R0 = (float*)(ws + 4096);              // Ne*512 floats (g, later k|v)
  float* g    = R0;
  float* kbuf = R0;
  float* vbuf = R0 + (size_t)Ne * C_DIM;
  float* R1 = R0 + (size_t)Ne * EMB_DIM;        // maxN*256 floats (h, later y)
  float* h    = R1;
  float* ybuf = R1;
  float* qbuf = R1 + (size_t)maxN * C_DIM;      // Nx*256 floats

  starts_kernel<<<1, 128, 0, stream>>>(bx, Nx, be, Ne, sx, se);

  int gyE = (Ne + 127) / 128;
  int gyX = (Nx + 127) / 128;
  int gyMax = gyE > gyX ? gyE : gyX;

  // fused launch: MLP1 (GELU, 4 col-blocks) + qproj (2 col-blocks), both
  // depend only on inputs -> 1152 balanced blocks (4.5/CU)
  gemm_kernel<<<dim3(6, gyMax), 256, 0, stream>>>(
      enc, W1, b1, g,    Ne, IN_DIM, EMB_DIM, 1,
      x,   Wq, bq, qbuf, Nx, C_DIM,  C_DIM,  0,
      4);

  // h = g @ W2 + b2  [Ne,256], then LN
  gemm_kernel<<<dim3(2, gyE), 256, 0, stream>>>(
      g, W2, b2, h, Ne, EMB_DIM, C_DIM, 0,
      g, W2, b2, h, Ne, EMB_DIM, C_DIM, 0,
      2);
  ln_kernel<<<(Ne + 3) / 4, 256, 0, stream>>>(h, lnw, lnb, Ne);

  // fused: k = h @ Wk + bk ; v = h @ Wv + bv (one A pass, 768 blocks)
  gemm_kernel<<<dim3(4, gyE), 256, 0, stream>>>(
      h, Wk, bk, kbuf, Ne, C_DIM, C_DIM, 0,
      h, Wv, bv, vbuf, Ne, C_DIM, C_DIM, 0,
      2);

  // attention -> ybuf (overwrites h region; h dead after k,v)
  attn_kernel<<<dim3(8192), 256, 0, stream>>>(
      qbuf, kbuf, vbuf, sx, se, msk, ybuf);

  // out = y @ Wp + bp
  gemm_kernel<<<dim3(2, gyX), 256, 0, stream>>>(
      ybuf, Wp, bp, out, Nx, C_DIM, C_DIM, 0,
      ybuf, Wp, bp, out, Nx, C_DIM, C_DIM, 0,
      2);
}

// Round 7
// 767.801 us; speedup vs baseline: 1.2085x; 1.2085x over previous
//
#include <hip/hip_runtime.h>
#include <math.h>

#define B_GROUPS 64
#define C_DIM 256
#define IN_DIM 512
#define EMB_DIM 512
#define NHEADS 8
#define HDIM 32

// ---------------- per-group starts via binary search ----------------
__global__ void starts_kernel(const int* __restrict__ bx, int nx,
                              const int* __restrict__ be, int ne,
                              int* __restrict__ sx, int* __restrict__ se) {
  int b = threadIdx.x;
  if (b > B_GROUPS) return;
  int lo = 0, hi = nx;
  while (lo < hi) { int mid = (lo + hi) >> 1; if (bx[mid] < b) lo = mid + 1; else hi = mid; }
  sx[b] = lo;
  lo = 0; hi = ne;
  while (lo < hi) { int mid = (lo + hi) >> 1; if (be[mid] < b) lo = mid + 1; else hi = mid; }
  se[b] = lo;
}

// ---------------- fp32 GEMM v4: 128x128 tile, 8x8/thread, BK=32 ------------
// SINGLE-buffer (R6 post-mortem: dbuf cost 188 VGPR -> 9.9% occ -> -25% perf;
// occupancy is the latency-hiding mechanism here, not manual pipelining).
// BK=32 halves barriers-per-FLOP vs BK=16: per k-step {stage -> barrier ->
// 32kk x 64 FMA -> barrier} = ~4096 VALU-cyc of compute per 2 barriers.
// launch_bounds(256,3): VGPR cap 168 -> 3 waves/SIMD; LDS 33.8KB -> 4 blk/CU;
// net 3 blocks/CU co-resident -> staging of one block hides under compute of
// the others. Two independent jobs per launch (split on blockIdx.x).
// Bank audit: A-stage scalar writes 2 lanes/bank (free m136); W-stage b128
// writes 8-way but 4 instr/step (~off path); compute reads broadcast/2-way.
// All register arrays fully unrolled, compile-time indexed (rule #20).
__global__ __launch_bounds__(256, 3) void gemm_kernel(
    const float* __restrict__ A0, const float* __restrict__ W0,
    const float* __restrict__ bias0, float* __restrict__ C0,
    int M0, int K0, int N0, int act0,
    const float* __restrict__ A1, const float* __restrict__ W1p,
    const float* __restrict__ bias1, float* __restrict__ C1,
    int M1, int K1, int N1, int act1,
    int xsplit) {
  __shared__ float As[32][132];
  __shared__ float Ws[32][132];

  int bxi = blockIdx.x;
  const float *A, *W, *bias; float* C; int M, K, N, act;
  if (bxi < xsplit) { A = A0; W = W0; bias = bias0; C = C0; M = M0; K = K0; N = N0; act = act0; }
  else { bxi -= xsplit; A = A1; W = W1p; bias = bias1; C = C1; M = M1; K = K1; N = N1; act = act1; }
  int bm = blockIdx.y * 128;
  int bn = bxi * 128;
  if (bm >= M) return;

  int tid = threadIdx.x;
  int tx = tid & 15, ty = tid >> 4;
  int ar  = tid >> 1;            // 0..127  (A-tile row)
  int acb = (tid & 1) * 16;      // 0 or 16 (A-tile col block, 16 wide)
  int wr  = tid >> 4;            // 0..15   (W-tile rows wr, wr+16)
  int wcb = (tid & 15) * 8;      // 0..120  (W-tile col block)

  int gr = bm + ar;
  bool arow_ok = gr < M;
  const float* aplane = &A[(size_t)(arow_ok ? gr : 0) * K + acb];
  const float* wplane = &W[(size_t)wr * N + bn + wcb];

  float acc[2][2][4][4] = {};

  for (int k0 = 0; k0 < K; k0 += 32) {
    {
      float4 a0 = make_float4(0.f,0.f,0.f,0.f), a1 = a0, a2 = a0, a3 = a0;
      if (arow_ok) {
        const float* ap = aplane + k0;
        a0 = *(const float4*)ap;       a1 = *(const float4*)(ap + 4);
        a2 = *(const float4*)(ap + 8); a3 = *(const float4*)(ap + 12);
      }
      As[acb +  0][ar] = a0.x; As[acb +  1][ar] = a0.y;
      As[acb +  2][ar] = a0.z; As[acb +  3][ar] = a0.w;
      As[acb +  4][ar] = a1.x; As[acb +  5][ar] = a1.y;
      As[acb +  6][ar] = a1.z; As[acb +  7][ar] = a1.w;
      As[acb +  8][ar] = a2.x; As[acb +  9][ar] = a2.y;
      As[acb + 10][ar] = a2.z; As[acb + 11][ar] = a2.w;
      As[acb + 12][ar] = a3.x; As[acb + 13][ar] = a3.y;
      As[acb + 14][ar] = a3.z; As[acb + 15][ar] = a3.w;
    }
    {
      const float* wp  = wplane + (size_t)k0 * N;
      const float* wp2 = wp + (size_t)16 * N;
      float4 w00 = *(const float4*)wp;  float4 w01 = *(const float4*)(wp + 4);
      float4 w10 = *(const float4*)wp2; float4 w11 = *(const float4*)(wp2 + 4);
      *(float4*)&Ws[wr][wcb]          = w00;
      *(float4*)&Ws[wr][wcb + 4]      = w01;
      *(float4*)&Ws[wr + 16][wcb]     = w10;
      *(float4*)&Ws[wr + 16][wcb + 4] = w11;
    }
    __syncthreads();
#pragma unroll 16
    for (int kk = 0; kk < 32; ++kk) {
      float a[2][4], w[2][4];
      *(float4*)a[0] = *(const float4*)&As[kk][ty * 4];
      *(float4*)a[1] = *(const float4*)&As[kk][64 + ty * 4];
      *(float4*)w[0] = *(const float4*)&Ws[kk][tx * 4];
      *(float4*)w[1] = *(const float4*)&Ws[kk][64 + tx * 4];
#pragma unroll
      for (int rh = 0; rh < 2; ++rh)
#pragma unroll
        for (int i = 0; i < 4; ++i) {
          float av = a[rh][i];
#pragma unroll
          for (int ch = 0; ch < 2; ++ch)
#pragma unroll
            for (int jj = 0; jj < 4; ++jj)
              acc[rh][ch][i][jj] += av * w[ch][jj];
        }
    }
    __syncthreads();
  }

  // ---- epilogue
  float bias_lo[4], bias_hi[4];
  *(float4*)bias_lo = *(const float4*)&bias[bn + tx * 4];
  *(float4*)bias_hi = *(const float4*)&bias[bn + 64 + tx * 4];
#pragma unroll
  for (int rh = 0; rh < 2; ++rh)
#pragma unroll
    for (int i = 0; i < 4; ++i) {
      int orow = bm + rh * 64 + ty * 4 + i;
      if (orow >= M) continue;
#pragma unroll
      for (int ch = 0; ch < 2; ++ch) {
        float o[4];
#pragma unroll
        for (int jj = 0; jj < 4; ++jj) {
          float vv = acc[rh][ch][i][jj] + (ch ? bias_hi[jj] : bias_lo[jj]);
          if (act) vv = 0.5f * vv * (1.0f + erff(vv * 0.70710678118654752f));
          o[jj] = vv;
        }
        *(float4*)&C[(size_t)orow * N + bn + ch * 64 + tx * 4] = *(float4*)o;
      }
    }
}

// ---------------- LayerNorm over last dim (256), in-place ----------------
__global__ __launch_bounds__(256) void ln_kernel(float* __restrict__ h,
    const float* __restrict__ w, const float* __restrict__ b, int M) {
  int row = blockIdx.x * 4 + (threadIdx.x >> 6);
  int lane = threadIdx.x & 63;
  if (row >= M) return;
  float4 v = *(const float4*)&h[(size_t)row * C_DIM + lane * 4];
  float s  = v.x + v.y + v.z + v.w;
  float s2 = v.x * v.x + v.y * v.y + v.z * v.z + v.w * v.w;
#pragma unroll
  for (int off = 1; off < 64; off <<= 1) { s += __shfl_xor(s, off); s2 += __shfl_xor(s2, off); }
  float mu  = s  * (1.0f / 256.0f);
  float var = s2 * (1.0f / 256.0f) - mu * mu;
  float inv = rsqrtf(var + 1e-5f);
  float4 wv = *(const float4*)&w[lane * 4];
  float4 bv = *(const float4*)&b[lane * 4];
  float4 o;
  o.x = (v.x - mu) * inv * wv.x + bv.x;
  o.y = (v.y - mu) * inv * wv.y + bv.y;
  o.z = (v.z - mu) * inv * wv.z + bv.z;
  o.w = (v.w - mu) * inv * wv.w + bv.w;
  *(float4*)&h[(size_t)row * C_DIM + lane * 4] = o;
}

// ---------------- ragged masked flash attention (v5, unchanged) ----------------
// Measured R4/R5: VGPR 52, occ 35%, VALUBusy 65%, conflicts ~0, 311 us.
__global__ __launch_bounds__(256, 4) void attn_kernel(const float* __restrict__ q,
    const float* __restrict__ k, const float* __restrict__ v,
    const int* __restrict__ sx, const int* __restrict__ se,
    const int* __restrict__ emask, float* __restrict__ y) {
  int bid = blockIdx.x;
  int work = ((bid & 7) << 10) + (bid >> 3);   // same (b,hd) -> same XCD
  int qt = work & 15;
  int bh = work >> 4;
  int b  = bh & 63;
  int hd = bh >> 6;

  int xs = sx[b], lx = sx[b + 1] - xs;
  if (qt * 32 >= lx) return;
  int es = se[b], le = se[b + 1] - es;

  __shared__ float Ks[64][36];
  __shared__ float Vs[64][36];
  __shared__ float Ps[32][68];
  __shared__ float Bs[64];

  int tid = threadIdx.x;
  int j  = tid & 7;
  int qg = tid >> 3;   // 0..31

  int qr = qt * 32 + qg;
  bool qok = qr < lx;
  float qreg[32];
  {
    const float* qp = &q[(size_t)(xs + (qok ? qr : 0)) * C_DIM + hd * HDIM];
#pragma unroll
    for (int d4 = 0; d4 < 8; ++d4) {
      float4 t4 = *(const float4*)&qp[d4 * 4];
      qreg[d4 * 4 + 0] = t4.x; qreg[d4 * 4 + 1] = t4.y;
      qreg[d4 * 4 + 2] = t4.z; qreg[d4 * 4 + 3] = t4.w;
    }
  }

  float acc[4] = {};
  float mrun = -INFINITY, lrun = 0.f;
  const float scale = 0.17677669529663689f;  // 1/sqrt(32)

  for (int kc = 0; kc < le; kc += 64) {
    int nk = le - kc; if (nk > 64) nk = 64;
    {
      int r = tid >> 3, c = (tid & 7) * 4;
#pragma unroll
      for (int it = 0; it < 2; ++it) {
        int rr = r + it * 32;
        float4 kv = make_float4(0.f, 0.f, 0.f, 0.f);
        float4 vv = make_float4(0.f, 0.f, 0.f, 0.f);
        if (rr < nk) {
          size_t base = (size_t)(es + kc + rr) * C_DIM + hd * HDIM + c;
          kv = *(const float4*)&k[base];
          vv = *(const float4*)&v[base];
        }
        *(float4*)&Ks[rr][c] = kv;
        *(float4*)&Vs[rr][c] = vv;
      }
      if (tid < 64)
        Bs[tid] = (tid < nk && emask[es + kc + tid]) ? 0.f : -1e30f;
    }
    __syncthreads();

    float bs[8];
#pragma unroll
    for (int t = 0; t < 8; ++t) bs[t] = Bs[t * 8 + j];

    float p[8];
#pragma unroll
    for (int t = 0; t < 8; ++t) {
      const float* krow = &Ks[t * 8 + j][0];
      float s = 0.f;
#pragma unroll
      for (int d4 = 0; d4 < 8; ++d4) {
        float4 kv = *(const float4*)&krow[d4 * 4];
        s += qreg[d4 * 4 + 0] * kv.x + qreg[d4 * 4 + 1] * kv.y
           + qreg[d4 * 4 + 2] * kv.z + qreg[d4 * 4 + 3] * kv.w;
      }
      p[t] = s * scale + bs[t];
    }

    float mloc = p[0];
#pragma unroll
    for (int t = 1; t < 8; ++t) mloc = fmaxf(mloc, p[t]);
    mloc = fmaxf(mloc, __shfl_xor(mloc, 1));
    mloc = fmaxf(mloc, __shfl_xor(mloc, 2));
    mloc = fmaxf(mloc, __shfl_xor(mloc, 4));
    float mnew = fmaxf(mrun, mloc);
    float alpha = __expf(mrun - mnew);
    float lloc = 0.f;
#pragma unroll
    for (int t = 0; t < 8; ++t) {
      float pe = __expf(p[t] - mnew);
      Ps[qg][t * 8 + j] = pe;
      lloc += pe;
    }
    lloc += __shfl_xor(lloc, 1);
    lloc += __shfl_xor(lloc, 2);
    lloc += __shfl_xor(lloc, 4);
    lrun = lrun * alpha + lloc;
    mrun = mnew;
#pragma unroll
    for (int d = 0; d < 4; ++d) acc[d] *= alpha;

#pragma unroll
    for (int kk4 = 0; kk4 < 16; ++kk4) {
      float pa[4];
      *(float4*)pa = *(const float4*)&Ps[qg][kk4 * 4];
#pragma unroll
      for (int u = 0; u < 4; ++u) {
        float4 vv = *(const float4*)&Vs[kk4 * 4 + u][j * 4];
        acc[0] += pa[u] * vv.x; acc[1] += pa[u] * vv.y;
        acc[2] += pa[u] * vv.z; acc[3] += pa[u] * vv.w;
      }
    }
    __syncthreads();
  }

  if (qok) {
    float invl = (lrun > 0.f) ? 1.0f / lrun : 0.f;
    float4 o = make_float4(acc[0] * invl, acc[1] * invl,
                           acc[2] * invl, acc[3] * invl);
    *(float4*)&y[(size_t)(xs + qr) * C_DIM + hd * HDIM + j * 4] = o;
  }
}

// ---------------- launch ----------------
extern "C" void kernel_launch(void* const* d_in, const int* in_sizes, int n_in,
                              void* d_out, int out_size, void* d_ws, size_t ws_size,
                              hipStream_t stream) {
  const float* x    = (const float*)d_in[0];
  const int*   bx   = (const int*)d_in[1];
  const int*   be   = (const int*)d_in[2];
  const float* enc  = (const float*)d_in[3];
  const int*   msk  = (const int*)d_in[4];
  const float* Wq   = (const float*)d_in[5];
  const float* bq   = (const float*)d_in[6];
  const float* Wk   = (const float*)d_in[7];
  const float* bk   = (const float*)d_in[8];
  const float* Wv   = (const float*)d_in[9];
  const float* bv   = (const float*)d_in[10];
  const float* Wp   = (const float*)d_in[11];
  const float* bp   = (const float*)d_in[12];
  const float* W1   = (const float*)d_in[13];
  const float* b1   = (const float*)d_in[14];
  const float* W2   = (const float*)d_in[15];
  const float* b2   = (const float*)d_in[16];
  const float* lnw  = (const float*)d_in[17];
  const float* lnb  = (const float*)d_in[18];
  float* out = (float*)d_out;

  int Nx = in_sizes[0] / C_DIM;
  int Ne = in_sizes[3] / IN_DIM;
  int maxN = Nx > Ne ? Nx : Ne;

  char* ws = (char*)d_ws;
  int* sx = (int*)ws;          // 65 ints
  int* se = sx + 80;           // 65 ints
  float* R0 = (float*)(ws + 4096);              // Ne*512 floats (g, later k|v)
  float* g    = R0;
  float* kbuf = R0;
  float* vbuf = R0 + (size_t)Ne * C_DIM;
  float* R1 = R0 + (size_t)Ne * EMB_DIM;        // maxN*256 floats (h, later y)
  float* h    = R1;
  float* ybuf = R1;
  float* qbuf = R1 + (size_t)maxN * C_DIM;      // Nx*256 floats

  starts_kernel<<<1, 128, 0, stream>>>(bx, Nx, be, Ne, sx, se);

  int gyE = (Ne + 127) / 128;
  int gyX = (Nx + 127) / 128;
  int gyMax = gyE > gyX ? gyE : gyX;

  // fused launch: MLP1 (GELU, 4 col-blocks) + qproj (2 col-blocks)
  gemm_kernel<<<dim3(6, gyMax), 256, 0, stream>>>(
      enc, W1, b1, g,    Ne, IN_DIM, EMB_DIM, 1,
      x,   Wq, bq, qbuf, Nx, C_DIM,  C_DIM,  0,
      4);

  // h = g @ W2 + b2  [Ne,256], then LN
  gemm_kernel<<<dim3(2, gyE), 256, 0, stream>>>(
      g, W2, b2, h, Ne, EMB_DIM, C_DIM, 0,
      g, W2, b2, h, Ne, EMB_DIM, C_DIM, 0,
      2);
  ln_kernel<<<(Ne + 3) / 4, 256, 0, stream>>>(h, lnw, lnb, Ne);

  // fused: k = h @ Wk + bk ; v = h @ Wv + bv (one A pass)
  gemm_kernel<<<dim3(4, gyE), 256, 0, stream>>>(
      h, Wk, bk, kbuf, Ne, C_DIM, C_DIM, 0,
      h, Wv, bv, vbuf, Ne, C_DIM, C_DIM, 0,
      2);

  // attention -> ybuf (overwrites h region; h dead after k,v)
  attn_kernel<<<dim3(8192), 256, 0, stream>>>(
      qbuf, kbuf, vbuf, sx, se, msk, ybuf);

  // out = y @ Wp + bp
  gemm_kernel<<<dim3(2, gyX), 256, 0, stream>>>(
      ybuf, Wp, bp, out, Nx, C_DIM, C_DIM, 0,
      ybuf, Wp, bp, out, Nx, C_DIM, C_DIM, 0,
      2);
}

// Round 8
// 491.016 us; speedup vs baseline: 1.8898x; 1.5637x over previous
//
#include <hip/hip_runtime.h>
#include <math.h>

#define B_GROUPS 64
#define C_DIM 256
#define IN_DIM 512
#define EMB_DIM 512
#define NHEADS 8
#define HDIM 32

typedef __attribute__((ext_vector_type(8))) short short8v;   // 8 bf16 = 4 VGPR
typedef __attribute__((ext_vector_type(4))) float float4v;   // mfma acc

// split fp32 -> bf16 hi (truncate, residual exact) + bf16 lo (rounded)
__device__ __forceinline__ void split2(float x, short& hi, short& lo) {
  unsigned u = __float_as_uint(x);
  hi = (short)(u >> 16);
  float l = x - __uint_as_float(u & 0xffff0000u);   // exact
  unsigned ul = __float_as_uint(l);
  lo = (short)((ul + 0x8000u) >> 16);
}

// global -> LDS direct copy, 16B per lane (dest linear: base + lane*16)
#define GLL(src, dst) __builtin_amdgcn_global_load_lds( \
    (const __attribute__((address_space(1))) void*)(src), \
    (__attribute__((address_space(3))) void*)(dst), 16, 0, 0)

// ---------------- per-group starts via binary search ----------------
__global__ void starts_kernel(const int* __restrict__ bx, int nx,
                              const int* __restrict__ be, int ne,
                              int* __restrict__ sx, int* __restrict__ se) {
  int b = threadIdx.x;
  if (b > B_GROUPS) return;
  int lo = 0, hi = nx;
  while (lo < hi) { int mid = (lo + hi) >> 1; if (bx[mid] < b) lo = mid + 1; else hi = mid; }
  sx[b] = lo;
  lo = 0; hi = ne;
  while (lo < hi) { int mid = (lo + hi) >> 1; if (be[mid] < b) lo = mid + 1; else hi = mid; }
  se[b] = lo;
}

// ---------------- prep: split enc,x ; transpose+split weights ----------------
// Wt layout [N][K] row-major so the MFMA B-operand frag (lane holds
// B[k-block][col=lane&15]) is a contiguous 16B LDS read.
__global__ __launch_bounds__(256) void prep_kernel(
    const float* __restrict__ enc, const float* __restrict__ x,
    const float* __restrict__ W1, const float* __restrict__ W2,
    const float* __restrict__ Wq, const float* __restrict__ Wk,
    const float* __restrict__ Wv, const float* __restrict__ Wp,
    short* __restrict__ encH, short* __restrict__ encL,
    short* __restrict__ xH, short* __restrict__ xL,
    short* __restrict__ wbuf, int nEnc, int nX) {
  int gid = blockIdx.x * blockDim.x + threadIdx.x;
  int stride = gridDim.x * blockDim.x;
  for (int i = gid; i < nEnc; i += stride) { short h,l; split2(enc[i],h,l); encH[i]=h; encL[i]=l; }
  for (int i = gid; i < nX;   i += stride) { short h,l; split2(x[i],h,l);   xH[i]=h;   xL[i]=l; }
  short* w1tH = wbuf;               short* w1tL = w1tH + 512*512;
  short* w2tH = w1tL + 512*512;     short* w2tL = w2tH + 256*512;
  short* wqtH = w2tL + 256*512;     short* wqtL = wqtH + 256*256;
  short* wktH = wqtL + 256*256;     short* wktL = wktH + 256*256;
  short* wvtH = wktL + 256*256;     short* wvtL = wvtH + 256*256;
  short* wptH = wvtL + 256*256;     short* wptL = wptH + 256*256;
  for (int i = gid; i < 512*512; i += stride) {
    int n = i >> 9, k = i & 511; short h,l;
    split2(W1[k*512 + n], h, l); w1tH[i] = h; w1tL[i] = l;
  }
  for (int i = gid; i < 256*512; i += stride) {
    int n = i >> 9, k = i & 511; short h,l;
    split2(W2[k*256 + n], h, l); w2tH[i] = h; w2tL[i] = l;
  }
  for (int i = gid; i < 256*256; i += stride) {
    int n = i >> 8, k = i & 255; int s = k*256 + n; short h,l;
    split2(Wq[s],h,l); wqtH[i]=h; wqtL[i]=l;
    split2(Wk[s],h,l); wktH[i]=h; wktL[i]=l;
    split2(Wv[s],h,l); wvtH[i]=h; wvtL[i]=l;
    split2(Wp[s],h,l); wptH[i]=h; wptL[i]=l;
  }
}

// ---------------- bf16x2-split MFMA GEMM: 128x128 tile, 4 waves ------------
// C = act(A@W + bias), A,W pre-split bf16 hi/lo; 3 mfma products per subtile
// (hi*hi + hi*lo + lo*hi), fp32 acc. M,N,K all multiples of 128/32 (exact).
// LDS granule swizzle g' = g ^ ((row>>1)&3): applied to gload_lds SOURCE
// (per-lane global gather, dest linear — m173/rule21) and to ds_read addr.
// Frag reads: 8 distinct 16B positions per 8-lane group -> conflict-free.
// Two jobs per launch (blockIdx.x split). Emit: 0=fp32 C, 1=bf16 hi/lo split.
__global__ __launch_bounds__(256) void gemm_mfma(
    const short* __restrict__ Ah0, const short* __restrict__ Al0,
    const short* __restrict__ Wh0, const short* __restrict__ Wl0,
    const float* __restrict__ bias0, float* __restrict__ Cf0,
    short* __restrict__ Ch0, short* __restrict__ Cl0,
    int K0, int N0, int act0, int emit0,
    const short* __restrict__ Ah1, const short* __restrict__ Al1,
    const short* __restrict__ Wh1, const short* __restrict__ Wl1,
    const float* __restrict__ bias1, float* __restrict__ Cf1,
    short* __restrict__ Ch1, short* __restrict__ Cl1,
    int K1, int N1, int act1, int emit1,
    int xsplit) {
  __shared__ short AsH[4096], AsL[4096], WsH[4096], WsL[4096];   // 4x8KB

  int bxi = blockIdx.x;
  const short *Ah, *Al, *Wh, *Wl; const float* bias; float* Cf; short *Ch, *Cl;
  int K, N, act, emit;
  if (bxi < xsplit) {
    Ah=Ah0; Al=Al0; Wh=Wh0; Wl=Wl0; bias=bias0; Cf=Cf0; Ch=Ch0; Cl=Cl0;
    K=K0; N=N0; act=act0; emit=emit0;
  } else {
    bxi -= xsplit;
    Ah=Ah1; Al=Al1; Wh=Wh1; Wl=Wl1; bias=bias1; Cf=Cf1; Ch=Ch1; Cl=Cl1;
    K=K1; N=N1; act=act1; emit=emit1;
  }
  int bm = blockIdx.y * 128;
  int bn = bxi * 128;

  int tid = threadIdx.x;
  int wv = tid >> 6, lane = tid & 63;
  int wr = (wv >> 1) * 64, wc = (wv & 1) * 64;   // wave's 64x64 output quadrant
  int laneM = lane & 15, laneK = lane >> 4;

  // ---- staging: wave wv covers granules [128wv, 128wv+128) of each buffer,
  // 2 gload_lds per buffer. Decode granule -> (row, swizzled-granule) for the
  // per-lane global source; LDS dest is linear.
  int Ga = wv * 128 + lane;
  int Gb = Ga + 64;
  int rA = Ga >> 2, gA = (Ga & 3) ^ ((rA >> 1) & 3);
  int rB = Gb >> 2, gB = (Gb & 3) ^ ((rB >> 1) & 3);
  const short* pAh0 = Ah + (size_t)(bm + rA) * K + gA * 8;
  const short* pAh1 = Ah + (size_t)(bm + rB) * K + gB * 8;
  const short* pAl0 = Al + (size_t)(bm + rA) * K + gA * 8;
  const short* pAl1 = Al + (size_t)(bm + rB) * K + gB * 8;
  const short* pWh0 = Wh + (size_t)(bn + rA) * K + gA * 8;
  const short* pWh1 = Wh + (size_t)(bn + rB) * K + gB * 8;
  const short* pWl0 = Wl + (size_t)(bn + rA) * K + gA * 8;
  const short* pWl1 = Wl + (size_t)(bn + rB) * K + gB * 8;
  short* dAH0 = AsH + wv * 1024;  short* dAH1 = dAH0 + 512;
  short* dAL0 = AsL + wv * 1024;  short* dAL1 = dAL0 + 512;
  short* dWH0 = WsH + wv * 1024;  short* dWH1 = dWH0 + 512;
  short* dWL0 = WsL + wv * 1024;  short* dWL1 = dWL0 + 512;

  // ---- frag read offsets (shorts), swizzled; loop-invariant
  int am[4], bo[4];
#pragma unroll
  for (int m = 0; m < 4; ++m) {
    int row = wr + m * 16 + laneM;
    am[m] = row * 32 + ((laneK ^ ((row >> 1) & 3)) << 3);
  }
#pragma unroll
  for (int n = 0; n < 4; ++n) {
    int row = wc + n * 16 + laneM;
    bo[n] = row * 32 + ((laneK ^ ((row >> 1) & 3)) << 3);
  }

  float4v acc[4][4];
  float4v z4 = {0.f, 0.f, 0.f, 0.f};
#pragma unroll
  for (int m = 0; m < 4; ++m)
#pragma unroll
    for (int n = 0; n < 4; ++n) acc[m][n] = z4;

  int nsteps = K >> 5;
  for (int t = 0; t < nsteps; ++t) {
    GLL(pAh0, dAH0); GLL(pAh1, dAH1);
    GLL(pAl0, dAL0); GLL(pAl1, dAL1);
    GLL(pWh0, dWH0); GLL(pWh1, dWH1);
    GLL(pWl0, dWL0); GLL(pWl1, dWL1);
    pAh0 += 32; pAh1 += 32; pAl0 += 32; pAl1 += 32;
    pWh0 += 32; pWh1 += 32; pWl0 += 32; pWl1 += 32;
    __syncthreads();   // drains vmcnt -> staged tile visible

    short8v ah[4], al[4], bh[4], bl[4];
#pragma unroll
    for (int m = 0; m < 4; ++m) {
      ah[m] = *(const short8v*)(AsH + am[m]);
      al[m] = *(const short8v*)(AsL + am[m]);
    }
#pragma unroll
    for (int n = 0; n < 4; ++n) {
      bh[n] = *(const short8v*)(WsH + bo[n]);
      bl[n] = *(const short8v*)(WsL + bo[n]);
    }
#pragma unroll
    for (int m = 0; m < 4; ++m)
#pragma unroll
      for (int n = 0; n < 4; ++n) {
        acc[m][n] = __builtin_amdgcn_mfma_f32_16x16x32_bf16(ah[m], bh[n], acc[m][n], 0, 0, 0);
        acc[m][n] = __builtin_amdgcn_mfma_f32_16x16x32_bf16(ah[m], bl[n], acc[m][n], 0, 0, 0);
        acc[m][n] = __builtin_amdgcn_mfma_f32_16x16x32_bf16(al[m], bh[n], acc[m][n], 0, 0, 0);
      }
    __syncthreads();   // protect LDS reuse next step
  }

  // ---- epilogue: D row = (lane>>4)*4 + r, col = lane&15 (m89/m91 layout)
  float bvn[4];
#pragma unroll
  for (int n = 0; n < 4; ++n) bvn[n] = bias[bn + wc + n * 16 + laneM];
#pragma unroll
  for (int m = 0; m < 4; ++m)
#pragma unroll
    for (int n = 0; n < 4; ++n)
#pragma unroll
      for (int r = 0; r < 4; ++r) {
        float vv = acc[m][n][r] + bvn[n];
        if (act) vv = 0.5f * vv * (1.0f + erff(vv * 0.70710678118654752f));
        size_t row = (size_t)(bm + wr + m * 16 + laneK * 4 + r);
        size_t idx = row * N + (bn + wc + n * 16 + laneM);
        if (emit == 0) {
          Cf[idx] = vv;
        } else {
          short hh, ll; split2(vv, hh, ll);
          Ch[idx] = hh; Cl[idx] = ll;
        }
      }
}

// ---------------- LayerNorm over last dim (256) -> split bf16 --------------
__global__ __launch_bounds__(256) void ln_kernel(const float* __restrict__ h,
    const float* __restrict__ w, const float* __restrict__ b,
    short* __restrict__ oH, short* __restrict__ oL, int M) {
  int row = blockIdx.x * 4 + (threadIdx.x >> 6);
  int lane = threadIdx.x & 63;
  if (row >= M) return;
  float4 v = *(const float4*)&h[(size_t)row * C_DIM + lane * 4];
  float s  = v.x + v.y + v.z + v.w;
  float s2 = v.x * v.x + v.y * v.y + v.z * v.z + v.w * v.w;
#pragma unroll
  for (int off = 1; off < 64; off <<= 1) { s += __shfl_xor(s, off); s2 += __shfl_xor(s2, off); }
  float mu  = s  * (1.0f / 256.0f);
  float var = s2 * (1.0f / 256.0f) - mu * mu;
  float inv = rsqrtf(var + 1e-5f);
  float4 wv = *(const float4*)&w[lane * 4];
  float4 bv = *(const float4*)&b[lane * 4];
  float o0 = (v.x - mu) * inv * wv.x + bv.x;
  float o1 = (v.y - mu) * inv * wv.y + bv.y;
  float o2 = (v.z - mu) * inv * wv.z + bv.z;
  float o3 = (v.w - mu) * inv * wv.w + bv.w;
  short h0,h1,h2,h3,l0,l1,l2,l3;
  split2(o0,h0,l0); split2(o1,h1,l1); split2(o2,h2,l2); split2(o3,h3,l3);
  size_t off = (size_t)row * C_DIM + lane * 4;
  *(short4*)&oH[off] = make_short4(h0,h1,h2,h3);
  *(short4*)&oL[off] = make_short4(l0,l1,l2,l3);
}

// ---------------- ragged masked flash attention (v5 + split-emit) ----------
// Measured R4-R7: VGPR 52, occ 35%, VALUBusy 65%, conflicts ~0, ~310 us.
// Epilogue now emits y as bf16 hi/lo (consumed by the MFMA P-projection).
__global__ __launch_bounds__(256, 4) void attn_kernel(const float* __restrict__ q,
    const float* __restrict__ k, const float* __restrict__ v,
    const int* __restrict__ sx, const int* __restrict__ se,
    const int* __restrict__ emask,
    short* __restrict__ yH, short* __restrict__ yL) {
  int bid = blockIdx.x;
  int work = ((bid & 7) << 10) + (bid >> 3);   // same (b,hd) -> same XCD
  int qt = work & 15;
  int bh = work >> 4;
  int b  = bh & 63;
  int hd = bh >> 6;

  int xs = sx[b], lx = sx[b + 1] - xs;
  if (qt * 32 >= lx) return;
  int es = se[b], le = se[b + 1] - es;

  __shared__ float Ks[64][36];
  __shared__ float Vs[64][36];
  __shared__ float Ps[32][68];
  __shared__ float Bs[64];

  int tid = threadIdx.x;
  int j  = tid & 7;
  int qg = tid >> 3;

  int qr = qt * 32 + qg;
  bool qok = qr < lx;
  float qreg[32];
  {
    const float* qp = &q[(size_t)(xs + (qok ? qr : 0)) * C_DIM + hd * HDIM];
#pragma unroll
    for (int d4 = 0; d4 < 8; ++d4) {
      float4 t4 = *(const float4*)&qp[d4 * 4];
      qreg[d4 * 4 + 0] = t4.x; qreg[d4 * 4 + 1] = t4.y;
      qreg[d4 * 4 + 2] = t4.z; qreg[d4 * 4 + 3] = t4.w;
    }
  }

  float acc[4] = {};
  float mrun = -INFINITY, lrun = 0.f;
  const float scale = 0.17677669529663689f;

  for (int kc = 0; kc < le; kc += 64) {
    int nk = le - kc; if (nk > 64) nk = 64;
    {
      int r = tid >> 3, c = (tid & 7) * 4;
#pragma unroll
      for (int it = 0; it < 2; ++it) {
        int rr = r + it * 32;
        float4 kv = make_float4(0.f, 0.f, 0.f, 0.f);
        float4 vv = make_float4(0.f, 0.f, 0.f, 0.f);
        if (rr < nk) {
          size_t base = (size_t)(es + kc + rr) * C_DIM + hd * HDIM + c;
          kv = *(const float4*)&k[base];
          vv = *(const float4*)&v[base];
        }
        *(float4*)&Ks[rr][c] = kv;
        *(float4*)&Vs[rr][c] = vv;
      }
      if (tid < 64)
        Bs[tid] = (tid < nk && emask[es + kc + tid]) ? 0.f : -1e30f;
    }
    __syncthreads();

    float bs[8];
#pragma unroll
    for (int t = 0; t < 8; ++t) bs[t] = Bs[t * 8 + j];

    float p[8];
#pragma unroll
    for (int t = 0; t < 8; ++t) {
      const float* krow = &Ks[t * 8 + j][0];
      float s = 0.f;
#pragma unroll
      for (int d4 = 0; d4 < 8; ++d4) {
        float4 kv = *(const float4*)&krow[d4 * 4];
        s += qreg[d4 * 4 + 0] * kv.x + qreg[d4 * 4 + 1] * kv.y
           + qreg[d4 * 4 + 2] * kv.z + qreg[d4 * 4 + 3] * kv.w;
      }
      p[t] = s * scale + bs[t];
    }

    float mloc = p[0];
#pragma unroll
    for (int t = 1; t < 8; ++t) mloc = fmaxf(mloc, p[t]);
    mloc = fmaxf(mloc, __shfl_xor(mloc, 1));
    mloc = fmaxf(mloc, __shfl_xor(mloc, 2));
    mloc = fmaxf(mloc, __shfl_xor(mloc, 4));
    float mnew = fmaxf(mrun, mloc);
    float alpha = __expf(mrun - mnew);
    float lloc = 0.f;
#pragma unroll
    for (int t = 0; t < 8; ++t) {
      float pe = __expf(p[t] - mnew);
      Ps[qg][t * 8 + j] = pe;
      lloc += pe;
    }
    lloc += __shfl_xor(lloc, 1);
    lloc += __shfl_xor(lloc, 2);
    lloc += __shfl_xor(lloc, 4);
    lrun = lrun * alpha + lloc;
    mrun = mnew;
#pragma unroll
    for (int d = 0; d < 4; ++d) acc[d] *= alpha;

#pragma unroll
    for (int kk4 = 0; kk4 < 16; ++kk4) {
      float pa[4];
      *(float4*)pa = *(const float4*)&Ps[qg][kk4 * 4];
#pragma unroll
      for (int u = 0; u < 4; ++u) {
        float4 vv = *(const float4*)&Vs[kk4 * 4 + u][j * 4];
        acc[0] += pa[u] * vv.x; acc[1] += pa[u] * vv.y;
        acc[2] += pa[u] * vv.z; acc[3] += pa[u] * vv.w;
      }
    }
    __syncthreads();
  }

  if (qok) {
    float invl = (lrun > 0.f) ? 1.0f / lrun : 0.f;
    short hh[4], ll[4];
#pragma unroll
    for (int d = 0; d < 4; ++d) split2(acc[d] * invl, hh[d], ll[d]);
    size_t off = (size_t)(xs + qr) * C_DIM + hd * HDIM + j * 4;
    *(short4*)&yH[off] = make_short4(hh[0], hh[1], hh[2], hh[3]);
    *(short4*)&yL[off] = make_short4(ll[0], ll[1], ll[2], ll[3]);
  }
}

// ---------------- launch ----------------
extern "C" void kernel_launch(void* const* d_in, const int* in_sizes, int n_in,
                              void* d_out, int out_size, void* d_ws, size_t ws_size,
                              hipStream_t stream) {
  const float* x    = (const float*)d_in[0];
  const int*   bx   = (const int*)d_in[1];
  const int*   be   = (const int*)d_in[2];
  const float* enc  = (const float*)d_in[3];
  const int*   msk  = (const int*)d_in[4];
  const float* Wq   = (const float*)d_in[5];
  const float* bq   = (const float*)d_in[6];
  const float* Wk   = (const float*)d_in[7];
  const float* bk   = (const float*)d_in[8];
  const float* Wv   = (const float*)d_in[9];
  const float* bv   = (const float*)d_in[10];
  const float* Wp   = (const float*)d_in[11];
  const float* bp   = (const float*)d_in[12];
  const float* W1   = (const float*)d_in[13];
  const float* b1   = (const float*)d_in[14];
  const float* W2   = (const float*)d_in[15];
  const float* b2   = (const float*)d_in[16];
  const float* lnw  = (const float*)d_in[17];
  const float* lnb  = (const float*)d_in[18];
  float* out = (float*)d_out;

  int Nx = in_sizes[0] / C_DIM;    // 24576 (multiple of 128 by construction)
  int Ne = in_sizes[3] / IN_DIM;   // 24576

  char* ws = (char*)d_ws;
  int* sx = (int*)ws;              // 65 ints
  int* se = sx + 80;

  // workspace plan (~128.5 MB) + d_out double-use (exactly Ne*512 shorts):
  short* encH = (short*)(ws + 4096);                 // Ne*512
  short* encL = encH + (size_t)Ne * IN_DIM;          // Ne*512
  short* xH   = encL + (size_t)Ne * IN_DIM;          // Nx*256 (later yH)
  short* xL   = xH + (size_t)Nx * C_DIM;             // Nx*256 (later yL)
  short* gLo  = xL + (size_t)Nx * C_DIM;             // Ne*512 (later vbuf f32)
  float* qbuf = (float*)(gLo + (size_t)Ne * EMB_DIM);// Nx*256 f32
  short* wbuf = (short*)(qbuf + (size_t)Nx * C_DIM); // 1.31M shorts
  // reuses:
  short* gHi  = (short*)d_out;     // G1 out hi; dead after G2
  float* hbuf = (float*)encH;      // Ne*256 f32 (enc splits dead after G1)
  short* hsH  = encL;              // Ne*256
  short* hsL  = encL + (size_t)Ne * C_DIM;
  float* kbuf = (float*)d_out;     // after G2 (g dead); dead before P writes out
  float* vbuf = (float*)gLo;

  short* w1tH = wbuf;               short* w1tL = w1tH + 512*512;
  short* w2tH = w1tL + 512*512;     short* w2tL = w2tH + 256*512;
  short* wqtH = w2tL + 256*512;     short* wqtL = wqtH + 256*256;
  short* wktH = wqtL + 256*256;     short* wktL = wktH + 256*256;
  short* wvtH = wktL + 256*256;     short* wvtL = wvtH + 256*256;
  short* wptH = wvtL + 256*256;     short* wptL = wptH + 256*256;

  prep_kernel<<<2048, 256, 0, stream>>>(enc, x, W1, W2, Wq, Wk, Wv, Wp,
      encH, encL, xH, xL, wbuf, Ne * IN_DIM, Nx * C_DIM);
  starts_kernel<<<1, 128, 0, stream>>>(bx, Nx, be, Ne, sx, se);

  int gy = Nx / 128;   // 192 (Nx == Ne)

  // G1: g = GELU(enc@W1+b1) -> split ; Q: qbuf = x@Wq+bq (fp32)
  gemm_mfma<<<dim3(6, gy), 256, 0, stream>>>(
      encH, encL, w1tH, w1tL, b1, nullptr, gHi, gLo, IN_DIM, EMB_DIM, 1, 1,
      xH,   xL,   wqtH, wqtL, bq, qbuf,  nullptr, nullptr, C_DIM, C_DIM, 0, 0,
      4);

  // G2: h = g@W2+b2 (fp32)
  gemm_mfma<<<dim3(2, gy), 256, 0, stream>>>(
      gHi, gLo, w2tH, w2tL, b2, hbuf, nullptr, nullptr, EMB_DIM, C_DIM, 0, 0,
      gHi, gLo, w2tH, w2tL, b2, hbuf, nullptr, nullptr, EMB_DIM, C_DIM, 0, 0,
      2);

  ln_kernel<<<(Ne + 3) / 4, 256, 0, stream>>>(hbuf, lnw, lnb, hsH, hsL, Ne);

  // KV fused: kbuf = hs@Wk+bk ; vbuf = hs@Wv+bv (fp32)
  gemm_mfma<<<dim3(4, gy), 256, 0, stream>>>(
      hsH, hsL, wktH, wktL, bk, kbuf, nullptr, nullptr, C_DIM, C_DIM, 0, 0,
      hsH, hsL, wvtH, wvtL, bv, vbuf, nullptr, nullptr, C_DIM, C_DIM, 0, 0,
      2);

  // attention -> y splits (over x region; x dead after G1)
  attn_kernel<<<dim3(8192), 256, 0, stream>>>(
      qbuf, kbuf, vbuf, sx, se, msk, xH, xL);

  // P: out = y@Wp+bp (fp32; overwrites kbuf region after attn finished)
  gemm_mfma<<<dim3(2, gy), 256, 0, stream>>>(
      xH, xL, wptH, wptL, bp, out, nullptr, nullptr, C_DIM, C_DIM, 0, 0,
      xH, xL, wptH, wptL, bp, out, nullptr, nullptr, C_DIM, C_DIM, 0, 0,
      2);
}

// Round 9
// 445.434 us; speedup vs baseline: 2.0832x; 1.1023x over previous
//
#include <hip/hip_runtime.h>
#include <math.h>

#define B_GROUPS 64
#define C_DIM 256
#define IN_DIM 512
#define EMB_DIM 512
#define NHEADS 8
#define HDIM 32

typedef __attribute__((ext_vector_type(8))) short short8v;   // 8 bf16 = 4 VGPR
typedef __attribute__((ext_vector_type(4))) float float4v;   // mfma acc

// split fp32 -> bf16 hi (truncate, residual exact) + bf16 lo (rounded)
__device__ __forceinline__ void split2(float x, short& hi, short& lo) {
  unsigned u = __float_as_uint(x);
  hi = (short)(u >> 16);
  float l = x - __uint_as_float(u & 0xffff0000u);   // exact
  unsigned ul = __float_as_uint(l);
  lo = (short)((ul + 0x8000u) >> 16);
}

// global -> LDS direct copy, 16B per lane (dest linear: base + lane*16)
#define GLL(src, dst) __builtin_amdgcn_global_load_lds( \
    (const __attribute__((address_space(1))) void*)(src), \
    (__attribute__((address_space(3))) void*)(dst), 16, 0, 0)

// ---------------- per-group starts via binary search ----------------
__global__ void starts_kernel(const int* __restrict__ bx, int nx,
                              const int* __restrict__ be, int ne,
                              int* __restrict__ sx, int* __restrict__ se) {
  int b = threadIdx.x;
  if (b > B_GROUPS) return;
  int lo = 0, hi = nx;
  while (lo < hi) { int mid = (lo + hi) >> 1; if (bx[mid] < b) lo = mid + 1; else hi = mid; }
  sx[b] = lo;
  lo = 0; hi = ne;
  while (lo < hi) { int mid = (lo + hi) >> 1; if (be[mid] < b) lo = mid + 1; else hi = mid; }
  se[b] = lo;
}

// ---------------- prep: split enc,x ; transpose+split weights ----------------
__global__ __launch_bounds__(256) void prep_kernel(
    const float* __restrict__ enc, const float* __restrict__ x,
    const float* __restrict__ W1, const float* __restrict__ W2,
    const float* __restrict__ Wq, const float* __restrict__ Wk,
    const float* __restrict__ Wv, const float* __restrict__ Wp,
    short* __restrict__ encH, short* __restrict__ encL,
    short* __restrict__ xH, short* __restrict__ xL,
    short* __restrict__ wbuf, int nEnc, int nX) {
  int gid = blockIdx.x * blockDim.x + threadIdx.x;
  int stride = gridDim.x * blockDim.x;
  for (int i = gid; i < nEnc; i += stride) { short h,l; split2(enc[i],h,l); encH[i]=h; encL[i]=l; }
  for (int i = gid; i < nX;   i += stride) { short h,l; split2(x[i],h,l);   xH[i]=h;   xL[i]=l; }
  short* w1tH = wbuf;               short* w1tL = w1tH + 512*512;
  short* w2tH = w1tL + 512*512;     short* w2tL = w2tH + 256*512;
  short* wqtH = w2tL + 256*512;     short* wqtL = wqtH + 256*256;
  short* wktH = wqtL + 256*256;     short* wktL = wktH + 256*256;
  short* wvtH = wktL + 256*256;     short* wvtL = wvtH + 256*256;
  short* wptH = wvtL + 256*256;     short* wptL = wptH + 256*256;
  for (int i = gid; i < 512*512; i += stride) {
    int n = i >> 9, k = i & 511; short h,l;
    split2(W1[k*512 + n], h, l); w1tH[i] = h; w1tL[i] = l;
  }
  for (int i = gid; i < 256*512; i += stride) {
    int n = i >> 9, k = i & 511; short h,l;
    split2(W2[k*256 + n], h, l); w2tH[i] = h; w2tL[i] = l;
  }
  for (int i = gid; i < 256*256; i += stride) {
    int n = i >> 8, k = i & 255; int s = k*256 + n; short h,l;
    split2(Wq[s],h,l); wqtH[i]=h; wqtL[i]=l;
    split2(Wk[s],h,l); wktH[i]=h; wktL[i]=l;
    split2(Wv[s],h,l); wvtH[i]=h; wvtL[i]=l;
    split2(Wp[s],h,l); wptH[i]=h; wptL[i]=l;
  }
}

// ---------------- bf16x2-split MFMA GEMM: 128x128 tile, 4 waves ------------
// Emit modes: 0 = fp32 std; 1 = split std [M][N]; 2 = split head-major
// [NH][Mrows][32] (Q/K attn operand layout); 3 = split V^T [NH][32][Mrows].
// Frag conventions harness-verified in R8 (passed): A row=lane&15,
// k=(lane>>4)*8+j; B col=lane&15; D col=lane&15, row=(lane>>4)*4+r.
__global__ __launch_bounds__(256) void gemm_mfma(
    const short* __restrict__ Ah0, const short* __restrict__ Al0,
    const short* __restrict__ Wh0, const short* __restrict__ Wl0,
    const float* __restrict__ bias0, float* __restrict__ Cf0,
    short* __restrict__ Ch0, short* __restrict__ Cl0,
    int K0, int N0, int act0, int emit0,
    const short* __restrict__ Ah1, const short* __restrict__ Al1,
    const short* __restrict__ Wh1, const short* __restrict__ Wl1,
    const float* __restrict__ bias1, float* __restrict__ Cf1,
    short* __restrict__ Ch1, short* __restrict__ Cl1,
    int K1, int N1, int act1, int emit1,
    int xsplit, int Mrows) {
  __shared__ short AsH[4096], AsL[4096], WsH[4096], WsL[4096];   // 4x8KB

  int bxi = blockIdx.x;
  const short *Ah, *Al, *Wh, *Wl; const float* bias; float* Cf; short *Ch, *Cl;
  int K, N, act, emit;
  if (bxi < xsplit) {
    Ah=Ah0; Al=Al0; Wh=Wh0; Wl=Wl0; bias=bias0; Cf=Cf0; Ch=Ch0; Cl=Cl0;
    K=K0; N=N0; act=act0; emit=emit0;
  } else {
    bxi -= xsplit;
    Ah=Ah1; Al=Al1; Wh=Wh1; Wl=Wl1; bias=bias1; Cf=Cf1; Ch=Ch1; Cl=Cl1;
    K=K1; N=N1; act=act1; emit=emit1;
  }
  int bm = blockIdx.y * 128;
  int bn = bxi * 128;

  int tid = threadIdx.x;
  int wv = tid >> 6, lane = tid & 63;
  int wr = (wv >> 1) * 64, wc = (wv & 1) * 64;
  int laneM = lane & 15, laneK = lane >> 4;

  int Ga = wv * 128 + lane;
  int Gb = Ga + 64;
  int rA = Ga >> 2, gA = (Ga & 3) ^ ((rA >> 1) & 3);
  int rB = Gb >> 2, gB = (Gb & 3) ^ ((rB >> 1) & 3);
  const short* pAh0 = Ah + (size_t)(bm + rA) * K + gA * 8;
  const short* pAh1 = Ah + (size_t)(bm + rB) * K + gB * 8;
  const short* pAl0 = Al + (size_t)(bm + rA) * K + gA * 8;
  const short* pAl1 = Al + (size_t)(bm + rB) * K + gB * 8;
  const short* pWh0 = Wh + (size_t)(bn + rA) * K + gA * 8;
  const short* pWh1 = Wh + (size_t)(bn + rB) * K + gB * 8;
  const short* pWl0 = Wl + (size_t)(bn + rA) * K + gA * 8;
  const short* pWl1 = Wl + (size_t)(bn + rB) * K + gB * 8;
  short* dAH0 = AsH + wv * 1024;  short* dAH1 = dAH0 + 512;
  short* dAL0 = AsL + wv * 1024;  short* dAL1 = dAL0 + 512;
  short* dWH0 = WsH + wv * 1024;  short* dWH1 = dWH0 + 512;
  short* dWL0 = WsL + wv * 1024;  short* dWL1 = dWL0 + 512;

  int am[4], bo[4];
#pragma unroll
  for (int m = 0; m < 4; ++m) {
    int row = wr + m * 16 + laneM;
    am[m] = row * 32 + ((laneK ^ ((row >> 1) & 3)) << 3);
  }
#pragma unroll
  for (int n = 0; n < 4; ++n) {
    int row = wc + n * 16 + laneM;
    bo[n] = row * 32 + ((laneK ^ ((row >> 1) & 3)) << 3);
  }

  float4v acc[4][4];
  float4v z4 = {0.f, 0.f, 0.f, 0.f};
#pragma unroll
  for (int m = 0; m < 4; ++m)
#pragma unroll
    for (int n = 0; n < 4; ++n) acc[m][n] = z4;

  int nsteps = K >> 5;
  for (int t = 0; t < nsteps; ++t) {
    GLL(pAh0, dAH0); GLL(pAh1, dAH1);
    GLL(pAl0, dAL0); GLL(pAl1, dAL1);
    GLL(pWh0, dWH0); GLL(pWh1, dWH1);
    GLL(pWl0, dWL0); GLL(pWl1, dWL1);
    pAh0 += 32; pAh1 += 32; pAl0 += 32; pAl1 += 32;
    pWh0 += 32; pWh1 += 32; pWl0 += 32; pWl1 += 32;
    __syncthreads();

    short8v ah[4], al[4], bh[4], bl[4];
#pragma unroll
    for (int m = 0; m < 4; ++m) {
      ah[m] = *(const short8v*)(AsH + am[m]);
      al[m] = *(const short8v*)(AsL + am[m]);
    }
#pragma unroll
    for (int n = 0; n < 4; ++n) {
      bh[n] = *(const short8v*)(WsH + bo[n]);
      bl[n] = *(const short8v*)(WsL + bo[n]);
    }
#pragma unroll
    for (int m = 0; m < 4; ++m)
#pragma unroll
      for (int n = 0; n < 4; ++n) {
        acc[m][n] = __builtin_amdgcn_mfma_f32_16x16x32_bf16(ah[m], bh[n], acc[m][n], 0, 0, 0);
        acc[m][n] = __builtin_amdgcn_mfma_f32_16x16x32_bf16(ah[m], bl[n], acc[m][n], 0, 0, 0);
        acc[m][n] = __builtin_amdgcn_mfma_f32_16x16x32_bf16(al[m], bh[n], acc[m][n], 0, 0, 0);
      }
    __syncthreads();
  }

  float bvn[4];
#pragma unroll
  for (int n = 0; n < 4; ++n) bvn[n] = bias[bn + wc + n * 16 + laneM];
#pragma unroll
  for (int m = 0; m < 4; ++m)
#pragma unroll
    for (int n = 0; n < 4; ++n)
#pragma unroll
      for (int r = 0; r < 4; ++r) {
        float vv = acc[m][n][r] + bvn[n];
        if (act) vv = 0.5f * vv * (1.0f + erff(vv * 0.70710678118654752f));
        size_t row = (size_t)(bm + wr + m * 16 + laneK * 4 + r);
        int col = bn + wc + n * 16 + laneM;
        if (emit == 0) {
          Cf[row * N + col] = vv;
        } else if (emit == 1) {
          short hh, ll; split2(vv, hh, ll);
          Ch[row * N + col] = hh; Cl[row * N + col] = ll;
        } else if (emit == 2) {   // head-major [NH][Mrows][32]
          size_t idx = ((size_t)(col >> 5) * Mrows + row) * 32 + (col & 31);
          short hh, ll; split2(vv, hh, ll);
          Ch[idx] = hh; Cl[idx] = ll;
        } else {                  // V^T [NH][32][Mrows]
          size_t idx = ((size_t)(col >> 5) * 32 + (col & 31)) * Mrows + row;
          short hh, ll; split2(vv, hh, ll);
          Ch[idx] = hh; Cl[idx] = ll;
        }
      }
}

// ---------------- LayerNorm over last dim (256) -> split bf16 --------------
__global__ __launch_bounds__(256) void ln_kernel(const float* __restrict__ h,
    const float* __restrict__ w, const float* __restrict__ b,
    short* __restrict__ oH, short* __restrict__ oL, int M) {
  int row = blockIdx.x * 4 + (threadIdx.x >> 6);
  int lane = threadIdx.x & 63;
  if (row >= M) return;
  float4 v = *(const float4*)&h[(size_t)row * C_DIM + lane * 4];
  float s  = v.x + v.y + v.z + v.w;
  float s2 = v.x * v.x + v.y * v.y + v.z * v.z + v.w * v.w;
#pragma unroll
  for (int off = 1; off < 64; off <<= 1) { s += __shfl_xor(s, off); s2 += __shfl_xor(s2, off); }
  float mu  = s  * (1.0f / 256.0f);
  float var = s2 * (1.0f / 256.0f) - mu * mu;
  float inv = rsqrtf(var + 1e-5f);
  float4 wv = *(const float4*)&w[lane * 4];
  float4 bv = *(const float4*)&b[lane * 4];
  float o0 = (v.x - mu) * inv * wv.x + bv.x;
  float o1 = (v.y - mu) * inv * wv.y + bv.y;
  float o2 = (v.z - mu) * inv * wv.z + bv.z;
  float o3 = (v.w - mu) * inv * wv.w + bv.w;
  short h0,h1,h2,h3,l0,l1,l2,l3;
  split2(o0,h0,l0); split2(o1,h1,l1); split2(o2,h2,l2); split2(o3,h3,l3);
  size_t off = (size_t)row * C_DIM + lane * 4;
  *(short4*)&oH[off] = make_short4(h0,h1,h2,h3);
  *(short4*)&oL[off] = make_short4(l0,l1,l2,l3);
}

// ---------------- MFMA flash attention -------------------------------------
// 4096 blocks (XCD-swizzled), 4 waves/block, each wave = one 16-row q-tile,
// NO barriers (wave-private LDS P tile only). Frag layouts = R8-verified GEMM
// conventions. KV loop over ABSOLUTE 64-aligned windows (keeps all short8v
// loads 16B-aligned for ragged es); out-of-window/masked lanes get -1e30 bias
// (self-healing online softmax, v5 scheme). QK^T 3-product hi/lo; P split to
// hi/lo through LDS (16x72 stride: frag reads 2-way free); PV 3-product.
__global__ __launch_bounds__(256, 4) void attn_mfma(
    const short* __restrict__ qh, const short* __restrict__ ql,   // [NH][Nx][32]
    const short* __restrict__ kh, const short* __restrict__ kl,   // [NH][Ne][32]
    const short* __restrict__ vh, const short* __restrict__ vl,   // [NH][32][Ne]
    const int* __restrict__ sx, const int* __restrict__ se,
    const int* __restrict__ emask,
    short* __restrict__ yH, short* __restrict__ yL,               // [Nx][256]
    int Nx, int Ne) {
  __shared__ short Ph[4][16][72];
  __shared__ short Pl[4][16][72];

  int bid = blockIdx.x;
  int work = ((bid & 7) << 9) + (bid >> 3);   // same (b,hd) group -> same XCD
  int qt8 = work & 7;
  int bh  = work >> 3;
  int b   = bh & 63;
  int hd  = bh >> 6;

  int xs = sx[b], lx = sx[b + 1] - xs;
  int es = se[b], le = se[b + 1] - es;

  int tid = threadIdx.x;
  int wv = tid >> 6, lane = tid & 63;
  int qt = qt8 * 4 + wv;                  // 0..31 q-tiles of 16
  if (qt * 16 >= lx) return;              // wave-uniform, no barriers in kernel

  int lm = lane & 15, lk = lane >> 4;

  // Q A-frag: row = qt*16+lm (clamped; tail rows masked at output), k = lk*8
  int qa = xs + min(qt * 16 + lm, lx - 1);
  size_t qoff = ((size_t)hd * Nx + qa) * 32 + lk * 8;
  short8v qfh = *(const short8v*)(qh + qoff);
  short8v qfl = *(const short8v*)(ql + qoff);

  float4v acc0 = {0.f,0.f,0.f,0.f}, acc1 = {0.f,0.f,0.f,0.f};
  float mrun[4] = {-INFINITY,-INFINITY,-INFINITY,-INFINITY};
  float lrun[4] = {0.f,0.f,0.f,0.f};
  const float scale = 0.17677669529663689f;  // 1/sqrt(32)

  int kvend = es + le;
  for (int kb = (es >> 6) << 6; kb < kvend; kb += 64) {
    // ---- QK^T: 4 kv-tiles of 16; B-frag = K rows (like Wt in the GEMM)
    float4v s[4]; float bias[4];
#pragma unroll
    for (int t = 0; t < 4; ++t) {
      int tok = kb + t * 16 + lm;
      int tokc = min(tok, Ne - 1);
      size_t koff = ((size_t)hd * Ne + tokc) * 32 + lk * 8;
      short8v kfh = *(const short8v*)(kh + koff);
      short8v kfl = *(const short8v*)(kl + koff);
      float4v z = {0.f,0.f,0.f,0.f};
      z = __builtin_amdgcn_mfma_f32_16x16x32_bf16(qfh, kfh, z, 0, 0, 0);
      z = __builtin_amdgcn_mfma_f32_16x16x32_bf16(qfh, kfl, z, 0, 0, 0);
      z = __builtin_amdgcn_mfma_f32_16x16x32_bf16(qfl, kfh, z, 0, 0, 0);
      s[t] = z;
      bias[t] = (tok >= es && tok < kvend && emask[tokc] != 0) ? 0.f : -1e30f;
    }

    // ---- online softmax: lane holds 4 q-rows (r) x 1 kv-col; row-reduce =
    // shfl_xor 1,2,4,8 within the 16-lane group (lane>>4 preserved).
#pragma unroll
    for (int r = 0; r < 4; ++r) {
      float p0 = s[0][r] * scale + bias[0];
      float p1 = s[1][r] * scale + bias[1];
      float p2 = s[2][r] * scale + bias[2];
      float p3 = s[3][r] * scale + bias[3];
      float mloc = fmaxf(fmaxf(p0, p1), fmaxf(p2, p3));
      mloc = fmaxf(mloc, __shfl_xor(mloc, 1));
      mloc = fmaxf(mloc, __shfl_xor(mloc, 2));
      mloc = fmaxf(mloc, __shfl_xor(mloc, 4));
      mloc = fmaxf(mloc, __shfl_xor(mloc, 8));
      float mnew = fmaxf(mrun[r], mloc);
      float alpha = __expf(mrun[r] - mnew);   // first tile: exp(-inf)=0
      float e0 = __expf(p0 - mnew), e1 = __expf(p1 - mnew);
      float e2 = __expf(p2 - mnew), e3 = __expf(p3 - mnew);
      float lloc = (e0 + e1) + (e2 + e3);
      lloc += __shfl_xor(lloc, 1);
      lloc += __shfl_xor(lloc, 2);
      lloc += __shfl_xor(lloc, 4);
      lloc += __shfl_xor(lloc, 8);
      lrun[r] = lrun[r] * alpha + lloc;
      mrun[r] = mnew;
      acc0[r] *= alpha; acc1[r] *= alpha;
      int q16 = lk * 4 + r;
      short hh, ll;
      split2(e0, hh, ll); Ph[wv][q16][lm]      = hh; Pl[wv][q16][lm]      = ll;
      split2(e1, hh, ll); Ph[wv][q16][16 + lm] = hh; Pl[wv][q16][16 + lm] = ll;
      split2(e2, hh, ll); Ph[wv][q16][32 + lm] = hh; Pl[wv][q16][32 + lm] = ll;
      split2(e3, hh, ll); Ph[wv][q16][48 + lm] = hh; Pl[wv][q16][48 + lm] = ll;
    }

    // ---- PV: A-frag = P from LDS (same-wave RAW, lgkmcnt-ordered),
    // B-frag = V^T rows (kv-contiguous). 2 kv-chunks of 32, 2 d-tiles.
#pragma unroll
    for (int c = 0; c < 2; ++c) {
      short8v pfh = *(const short8v*)&Ph[wv][lm][c * 32 + lk * 8];
      short8v pfl = *(const short8v*)&Pl[wv][lm][c * 32 + lk * 8];
      int tokb = kb + c * 32 + lk * 8;
      if (tokb > Ne - 8) tokb = Ne - 8;      // clamped junk is masked (P=0)
      size_t v0 = ((size_t)hd * 32 + lm) * Ne + tokb;
      size_t v1 = ((size_t)hd * 32 + 16 + lm) * Ne + tokb;
      short8v v0h = *(const short8v*)(vh + v0);
      short8v v0l = *(const short8v*)(vl + v0);
      short8v v1h = *(const short8v*)(vh + v1);
      short8v v1l = *(const short8v*)(vl + v1);
      acc0 = __builtin_amdgcn_mfma_f32_16x16x32_bf16(pfh, v0h, acc0, 0, 0, 0);
      acc0 = __builtin_amdgcn_mfma_f32_16x16x32_bf16(pfh, v0l, acc0, 0, 0, 0);
      acc0 = __builtin_amdgcn_mfma_f32_16x16x32_bf16(pfl, v0h, acc0, 0, 0, 0);
      acc1 = __builtin_amdgcn_mfma_f32_16x16x32_bf16(pfh, v1h, acc1, 0, 0, 0);
      acc1 = __builtin_amdgcn_mfma_f32_16x16x32_bf16(pfh, v1l, acc1, 0, 0, 0);
      acc1 = __builtin_amdgcn_mfma_f32_16x16x32_bf16(pfl, v1h, acc1, 0, 0, 0);
    }
  }

  // ---- output: q = qt*16 + lk*4 + r, d = dt*16 + lm; emit split bf16
#pragma unroll
  for (int r = 0; r < 4; ++r) {
    int q = qt * 16 + lk * 4 + r;
    if (q >= lx) continue;
    float invl = (lrun[r] > 0.f) ? 1.0f / lrun[r] : 0.f;
    size_t base = (size_t)(xs + q) * C_DIM + hd * HDIM;
    short hh, ll;
    split2(acc0[r] * invl, hh, ll); yH[base + lm] = hh;      yL[base + lm] = ll;
    split2(acc1[r] * invl, hh, ll); yH[base + 16 + lm] = hh; yL[base + 16 + lm] = ll;
  }
}

// ---------------- launch ----------------
extern "C" void kernel_launch(void* const* d_in, const int* in_sizes, int n_in,
                              void* d_out, int out_size, void* d_ws, size_t ws_size,
                              hipStream_t stream) {
  const float* x    = (const float*)d_in[0];
  const int*   bx   = (const int*)d_in[1];
  const int*   be   = (const int*)d_in[2];
  const float* enc  = (const float*)d_in[3];
  const int*   msk  = (const int*)d_in[4];
  const float* Wq   = (const float*)d_in[5];
  const float* bq   = (const float*)d_in[6];
  const float* Wk   = (const float*)d_in[7];
  const float* bk   = (const float*)d_in[8];
  const float* Wv   = (const float*)d_in[9];
  const float* bv   = (const float*)d_in[10];
  const float* Wp   = (const float*)d_in[11];
  const float* bp   = (const float*)d_in[12];
  const float* W1   = (const float*)d_in[13];
  const float* b1   = (const float*)d_in[14];
  const float* W2   = (const float*)d_in[15];
  const float* b2   = (const float*)d_in[16];
  const float* lnw  = (const float*)d_in[17];
  const float* lnb  = (const float*)d_in[18];
  float* out = (float*)d_out;

  int Nx = in_sizes[0] / C_DIM;    // 24576 (multiple of 128, == Ne)
  int Ne = in_sizes[3] / IN_DIM;

  char* ws = (char*)d_ws;
  int* sx = (int*)ws;
  int* se = sx + 80;

  short* encH = (short*)(ws + 4096);                 // Ne*512
  short* encL = encH + (size_t)Ne * IN_DIM;          // Ne*512
  short* xH   = encL + (size_t)Ne * IN_DIM;          // Nx*256 (later yH)
  short* xL   = xH + (size_t)Nx * C_DIM;             // Nx*256 (later yL)
  short* gLo  = xL + (size_t)Nx * C_DIM;             // Ne*512 (later vH|vL)
  short* qHh  = gLo + (size_t)Ne * EMB_DIM;          // Nx*256
  short* qHl  = qHh + (size_t)Nx * C_DIM;            // Nx*256
  short* wbuf = qHl + (size_t)Nx * C_DIM;            // 1.31M shorts
  // reuses:
  short* gHi  = (short*)d_out;                       // G1 hi; dead after G2
  float* hbuf = (float*)encH;                        // enc splits dead post-G1
  short* hsH  = encL;
  short* hsL  = encL + (size_t)Ne * C_DIM;
  short* kH   = (short*)d_out;                       // after G2 (g dead)
  short* kL   = kH + (size_t)Ne * C_DIM;
  short* vH   = gLo;                                 // gLo dead after G2
  short* vL   = gLo + (size_t)Ne * C_DIM;

  short* w1tH = wbuf;               short* w1tL = w1tH + 512*512;
  short* w2tH = w1tL + 512*512;     short* w2tL = w2tH + 256*512;
  short* wqtH = w2tL + 256*512;     short* wqtL = wqtH + 256*256;
  short* wktH = wqtL + 256*256;     short* wktL = wktH + 256*256;
  short* wvtH = wktL + 256*256;     short* wvtL = wvtH + 256*256;
  short* wptH = wvtL + 256*256;     short* wptL = wptH + 256*256;

  prep_kernel<<<2048, 256, 0, stream>>>(enc, x, W1, W2, Wq, Wk, Wv, Wp,
      encH, encL, xH, xL, wbuf, Ne * IN_DIM, Nx * C_DIM);
  starts_kernel<<<1, 128, 0, stream>>>(bx, Nx, be, Ne, sx, se);

  int gy = Nx / 128;

  // G1: g = GELU(enc@W1+b1) -> split std ; Q: x@Wq+bq -> head-major split
  gemm_mfma<<<dim3(6, gy), 256, 0, stream>>>(
      encH, encL, w1tH, w1tL, b1, nullptr, gHi, gLo, IN_DIM, EMB_DIM, 1, 1,
      xH,   xL,   wqtH, wqtL, bq, nullptr, qHh, qHl,  C_DIM, C_DIM,  0, 2,
      4, Nx);

  // G2: h = g@W2+b2 (fp32)
  gemm_mfma<<<dim3(2, gy), 256, 0, stream>>>(
      gHi, gLo, w2tH, w2tL, b2, hbuf, nullptr, nullptr, EMB_DIM, C_DIM, 0, 0,
      gHi, gLo, w2tH, w2tL, b2, hbuf, nullptr, nullptr, EMB_DIM, C_DIM, 0, 0,
      2, Nx);

  ln_kernel<<<(Ne + 3) / 4, 256, 0, stream>>>(hbuf, lnw, lnb, hsH, hsL, Ne);

  // KV: K -> head-major split ; V -> V^T split (one A pass)
  gemm_mfma<<<dim3(4, gy), 256, 0, stream>>>(
      hsH, hsL, wktH, wktL, bk, nullptr, kH, kL, C_DIM, C_DIM, 0, 2,
      hsH, hsL, wvtH, wvtL, bv, nullptr, vH, vL, C_DIM, C_DIM, 0, 3,
      2, Nx);

  // MFMA attention -> y splits (over x region; x dead after G1)
  attn_mfma<<<dim3(4096), 256, 0, stream>>>(
      qHh, qHl, kH, kL, vH, vL, sx, se, msk, xH, xL, Nx, Ne);

  // P: out = y@Wp+bp (fp32)
  gemm_mfma<<<dim3(2, gy), 256, 0, stream>>>(
      xH, xL, wptH, wptL, bp, out, nullptr, nullptr, C_DIM, C_DIM, 0, 0,
      xH, xL, wptH, wptL, bp, out, nullptr, nullptr, C_DIM, C_DIM, 0, 0,
      2, Nx);
}